// Round 1
// baseline (1453.712 us; speedup 1.0000x reference)
//
#include <hip/hip_runtime.h>
#include <hip/hip_bf16.h>
#include <math.h>

// Problem constants (from reference)
#define NN 50000
#define EE 1600000
#define NFEAT 256
#define NHID 128

// ---------------------------------------------------------------------------
// utility: zero an int buffer
__global__ void k_zero_i32(int* __restrict__ p, int n) {
    int i = blockIdx.x * 256 + threadIdx.x;
    if (i < n) p[i] = 0;
}

// degree histogram
__global__ void k_deg(const int* __restrict__ row, int* __restrict__ deg, int e) {
    int i = blockIdx.x * 256 + threadIdx.x;
    if (i < e) atomicAdd(&deg[row[i]], 1);
}

// scan step 1: per-block (256-elem) sums
__global__ void k_scan1(const int* __restrict__ deg, int* __restrict__ bsum, int n) {
    __shared__ int s[256];
    int t = threadIdx.x;
    int i = blockIdx.x * 256 + t;
    s[t] = (i < n) ? deg[i] : 0;
    __syncthreads();
    for (int off = 128; off > 0; off >>= 1) {
        if (t < off) s[t] += s[t + off];
        __syncthreads();
    }
    if (t == 0) bsum[blockIdx.x] = s[0];
}

// scan step 2: serial exclusive scan of block sums (nb ~ 196, negligible)
__global__ void k_scan2(int* __restrict__ bsum, int nb) {
    if (blockIdx.x == 0 && threadIdx.x == 0) {
        int acc = 0;
        for (int i = 0; i < nb; ++i) { int t = bsum[i]; bsum[i] = acc; acc += t; }
    }
}

// scan step 3: full exclusive scan -> row_ptr, cursor; also inv_deg
__global__ void k_scan3(const int* __restrict__ deg, const int* __restrict__ bsum,
                        int* __restrict__ rp, int* __restrict__ cursor,
                        float* __restrict__ invd, int n) {
    __shared__ int buf[2][256];
    int t = threadIdx.x;
    int i = blockIdx.x * 256 + t;
    int v = (i < n) ? deg[i] : 0;
    buf[0][t] = v;
    __syncthreads();
    int sel = 0;
    for (int off = 1; off < 256; off <<= 1) {
        int x = buf[sel][t];
        if (t >= off) x += buf[sel][t - off];
        buf[sel ^ 1][t] = x;
        sel ^= 1;
        __syncthreads();
    }
    int incl = buf[sel][t];
    int excl = incl - v;
    if (i < n) {
        int base = bsum[blockIdx.x];
        rp[i] = base + excl;
        cursor[i] = base + excl;
        invd[i] = 1.0f / fmaxf((float)v, 1.0f);
        if (i == n - 1) rp[n] = base + incl;  // == E
    }
}

// bucket fill: csr_col[pos] = col[e]
__global__ void k_fill(const int* __restrict__ row, const int* __restrict__ col,
                       int* __restrict__ cursor, int* __restrict__ ci, int e) {
    int i = blockIdx.x * 256 + threadIdx.x;
    if (i < e) {
        int p = atomicAdd(&cursor[row[i]], 1);
        ci[p] = col[i];
    }
}

// ---------------------------------------------------------------------------
// SAGE aggregation: one wave per node, gather-sum neighbor rows, scale by 1/deg
template <int D>
__global__ __launch_bounds__(256) void k_agg(const float* __restrict__ X,
                                             const int* __restrict__ rp,
                                             const int* __restrict__ ci,
                                             const float* __restrict__ invd,
                                             float* __restrict__ AGG, int n) {
    constexpr int V = D / 64;  // floats per lane (4 for D=256, 2 for D=128)
    int node = (blockIdx.x * blockDim.x + threadIdx.x) >> 6;
    int lane = threadIdx.x & 63;
    if (node >= n) return;
    int s = rp[node], e = rp[node + 1];
    float acc[V];
#pragma unroll
    for (int q = 0; q < V; ++q) acc[q] = 0.0f;
    const int cbase = lane * V;
    for (int j = s; j < e; ++j) {
        int nb = ci[j];
        const float* xr = X + (size_t)nb * D + cbase;
#pragma unroll
        for (int q = 0; q < V; ++q) acc[q] += xr[q];
    }
    float scl = invd[node];
    float* out = AGG + (size_t)node * D + cbase;
#pragma unroll
    for (int q = 0; q < V; ++q) out[q] = acc[q] * scl;
}

// ---------------------------------------------------------------------------
// Dual-source register-tiled GEMM, BN=128 fixed (output width always 128).
// C[r][c] = sum_k A1[r][k]*Wa[k][c] (k<K1)  +  sum_k A2[r][k]*Wb[k][c] (k<K2)
// EPI 0: C = val + (b1?b1[c]:0)
// EPI 1: gated skip + relu:  z=sigmoid(val+b1[c]+b2[c]); C=relu(z*A2 + (1-z)*A1)
// EPI 2: gated skip (no relu)
template <int K1, int K2, int EPI>
__global__ __launch_bounds__(256) void k_gemm(const float* __restrict__ A1,
                                              const float* __restrict__ A2,
                                              const float* __restrict__ Wa,
                                              const float* __restrict__ Wb,
                                              const float* __restrict__ b1,
                                              const float* __restrict__ b2,
                                              float* __restrict__ C, int n) {
    constexpr int K = K1 + K2;
    constexpr int BM = 128, BK = 32;
    __shared__ float sA[BM][BK + 4];  // pad keeps float4 align + spreads banks
    __shared__ float sW[BK][128];

    const int tid = threadIdx.x;
    const int tx = tid & 15, ty = tid >> 4;
    const int row0 = blockIdx.x * BM;

    float acc[8][8];
#pragma unroll
    for (int m = 0; m < 8; ++m)
#pragma unroll
        for (int j = 0; j < 8; ++j) acc[m][j] = 0.0f;

    for (int kt = 0; kt < K / BK; ++kt) {
        const int kbase = kt * BK;
        const float* src;
        int stride, koff;
        if (kbase < K1) { src = A1; stride = K1; koff = kbase; }
        else            { src = A2; stride = K2; koff = kbase - K1; }

        // stage A tile: 128 rows x 32 cols = 1024 float4, 4 per thread
#pragma unroll
        for (int i = 0; i < 4; ++i) {
            int f = tid + i * 256;
            int r = f >> 3, c4 = (f & 7) << 2;
            float4 v = make_float4(0.f, 0.f, 0.f, 0.f);
            int gr = row0 + r;
            if (gr < n)
                v = *reinterpret_cast<const float4*>(src + (size_t)gr * stride + koff + c4);
            *reinterpret_cast<float4*>(&sA[r][c4]) = v;
        }
        // stage W tile: 32 rows x 128 cols = 1024 float4, 4 per thread
        const float* wsrc = (kbase < K1) ? (Wa + (size_t)kbase * 128)
                                         : (Wb + (size_t)(kbase - K1) * 128);
#pragma unroll
        for (int i = 0; i < 4; ++i) {
            int f = tid + i * 256;
            int r = f >> 5, c4 = (f & 31) << 2;
            *reinterpret_cast<float4*>(&sW[r][c4]) =
                *reinterpret_cast<const float4*>(wsrc + (size_t)r * 128 + c4);
        }
        __syncthreads();

#pragma unroll
        for (int k = 0; k < BK; ++k) {
            float a[8];
#pragma unroll
            for (int m = 0; m < 8; ++m) a[m] = sA[ty + 16 * m][k];
            float4 bv0 = *reinterpret_cast<const float4*>(&sW[k][4 * tx]);
            float4 bv1 = *reinterpret_cast<const float4*>(&sW[k][64 + 4 * tx]);
            float bj[8] = {bv0.x, bv0.y, bv0.z, bv0.w, bv1.x, bv1.y, bv1.z, bv1.w};
#pragma unroll
            for (int m = 0; m < 8; ++m)
#pragma unroll
                for (int j = 0; j < 8; ++j) acc[m][j] = fmaf(a[m], bj[j], acc[m][j]);
        }
        __syncthreads();
    }

    // epilogue
#pragma unroll
    for (int m = 0; m < 8; ++m) {
        int r = row0 + ty + 16 * m;
        if (r >= n) continue;
#pragma unroll
        for (int half = 0; half < 2; ++half) {
#pragma unroll
            for (int jj = 0; jj < 4; ++jj) {
                int j = half * 4 + jj;
                int c = half * 64 + 4 * tx + jj;
                float v = acc[m][j];
                if (EPI == 0) {
                    if (b1) v += b1[c];
                    C[(size_t)r * 128 + c] = v;
                } else {
                    v += b1[c] + b2[c];
                    float z = 1.0f / (1.0f + __expf(-v));
                    float o = A2[(size_t)r * 128 + c];
                    float s = A1[(size_t)r * 128 + c];
                    float out = z * o + (1.0f - z) * s;
                    if (EPI == 1) out = fmaxf(out, 0.0f);
                    C[(size_t)r * 128 + c] = out;
                }
            }
        }
    }
}

// ---------------------------------------------------------------------------
extern "C" void kernel_launch(void* const* d_in, const int* in_sizes, int n_in,
                              void* d_out, int out_size, void* d_ws, size_t ws_size,
                              hipStream_t stream) {
    const float* x    = (const float*)d_in[0];
    const int*   row  = (const int*)d_in[1];
    const int*   col  = (const int*)d_in[2];
    const float* W_sc = (const float*)d_in[3];
    const float* W_ci = (const float*)d_in[4];
    const float* b_ci = (const float*)d_in[5];
    const float* W_co = (const float*)d_in[6];
    const float* b_co = (const float*)d_in[7];
    const float* W0   = (const float*)d_in[8];
    const float* b0   = (const float*)d_in[9];
    const float* W1   = (const float*)d_in[10];
    const float* b1   = (const float*)d_in[11];
    const float* W2   = (const float*)d_in[12];
    const float* b2   = (const float*)d_in[13];
    const float* Wf   = (const float*)d_in[14];
    const float* bf   = (const float*)d_in[15];
    float* out = (float*)d_out;

    // workspace carve-up (all 256B aligned)
    char* p = (char*)d_ws;
    auto alloc = [&](size_t bytes) {
        char* q = p;
        p += (bytes + 255) & ~(size_t)255;
        return q;
    };
    int*   degi   = (int*)alloc(NN * 4);
    int*   rp     = (int*)alloc((NN + 1) * 4);
    int*   cursor = (int*)alloc(NN * 4);
    int*   bsum   = (int*)alloc(256 * 4);
    float* invd   = (float*)alloc(NN * 4);
    int*   ci     = (int*)alloc(EE * 4);
    float* agg    = (float*)alloc((size_t)NN * 256 * 4);
    float* sc     = (float*)alloc((size_t)NN * 128 * 4);
    float* t0     = (float*)alloc((size_t)NN * 128 * 4);
    float* t1     = (float*)alloc((size_t)NN * 128 * 4);

    const int NB_N  = (NN + 255) / 256;   // 196
    const int NB_E  = (EE + 255) / 256;   // 6250
    const int GB    = (NN + 127) / 128;   // 391 gemm row-blocks
    const int AGG_B = (NN + 3) / 4;       // 12500 blocks (4 waves/block, 1 node/wave)

    // ---- graph structure (rebuilt every call; ws is poisoned) ----
    k_zero_i32<<<NB_N, 256, 0, stream>>>(degi, NN);
    k_deg<<<NB_E, 256, 0, stream>>>(row, degi, EE);
    k_scan1<<<NB_N, 256, 0, stream>>>(degi, bsum, NN);
    k_scan2<<<1, 1, 0, stream>>>(bsum, NB_N);
    k_scan3<<<NB_N, 256, 0, stream>>>(degi, bsum, rp, cursor, invd, NN);
    k_fill<<<NB_E, 256, 0, stream>>>(row, col, cursor, ci, EE);

    // sc = x @ W_sc  (shared across all three gated skips)
    k_gemm<256, 0, 0><<<GB, 256, 0, stream>>>(x, nullptr, W_sc, nullptr,
                                              nullptr, nullptr, sc, NN);

    // ---- layer 0 ----
    k_agg<256><<<AGG_B, 256, 0, stream>>>(x, rp, ci, invd, agg, NN);
    k_gemm<256, 256, 0><<<GB, 256, 0, stream>>>(x, agg, W0, W0 + 256 * 128,
                                                b0, nullptr, t0, NN);        // o1
    k_gemm<128, 128, 1><<<GB, 256, 0, stream>>>(sc, t0, W_ci, W_co,
                                                b_ci, b_co, t1, NN);         // o3

    // ---- layer 1 ----
    k_agg<128><<<AGG_B, 256, 0, stream>>>(t1, rp, ci, invd, agg, NN);
    k_gemm<128, 128, 0><<<GB, 256, 0, stream>>>(t1, agg, W1, W1 + 128 * 128,
                                                b1, nullptr, t0, NN);        // o4
    k_gemm<128, 128, 1><<<GB, 256, 0, stream>>>(sc, t0, W_ci, W_co,
                                                b_ci, b_co, t1, NN);         // o6

    // ---- layer 2 ----
    k_agg<128><<<AGG_B, 256, 0, stream>>>(t1, rp, ci, invd, agg, NN);
    k_gemm<128, 128, 0><<<GB, 256, 0, stream>>>(t1, agg, W2, W2 + 128 * 128,
                                                b2, nullptr, t0, NN);        // o7
    k_gemm<128, 128, 2><<<GB, 256, 0, stream>>>(sc, t0, W_ci, W_co,
                                                b_ci, b_co, t1, NN);         // o8

    // ---- classifier ----
    k_gemm<128, 0, 0><<<GB, 256, 0, stream>>>(t1, nullptr, Wf, nullptr,
                                              bf, nullptr, out, NN);
}

// Round 2
// 1292.863 us; speedup vs baseline: 1.1244x; 1.1244x over previous
//
#include <hip/hip_runtime.h>
#include <hip/hip_bf16.h>
#include <math.h>

// Problem constants (from reference)
#define NN 50000
#define EE 1600000
#define NFEAT 256
#define NHID 128

// ---------------------------------------------------------------------------
// utility: zero an int buffer
__global__ void k_zero_i32(int* __restrict__ p, int n) {
    int i = blockIdx.x * 256 + threadIdx.x;
    if (i < n) p[i] = 0;
}

// degree histogram
__global__ void k_deg(const int* __restrict__ row, int* __restrict__ deg, int e) {
    int i = blockIdx.x * 256 + threadIdx.x;
    if (i < e) atomicAdd(&deg[row[i]], 1);
}

// scan step 1: per-block (256-elem) sums
__global__ void k_scan1(const int* __restrict__ deg, int* __restrict__ bsum, int n) {
    __shared__ int s[256];
    int t = threadIdx.x;
    int i = blockIdx.x * 256 + t;
    s[t] = (i < n) ? deg[i] : 0;
    __syncthreads();
    for (int off = 128; off > 0; off >>= 1) {
        if (t < off) s[t] += s[t + off];
        __syncthreads();
    }
    if (t == 0) bsum[blockIdx.x] = s[0];
}

// scan step 2: serial exclusive scan of block sums (nb ~ 196, negligible)
__global__ void k_scan2(int* __restrict__ bsum, int nb) {
    if (blockIdx.x == 0 && threadIdx.x == 0) {
        int acc = 0;
        for (int i = 0; i < nb; ++i) { int t = bsum[i]; bsum[i] = acc; acc += t; }
    }
}

// scan step 3: full exclusive scan -> row_ptr, cursor; also inv_deg
__global__ void k_scan3(const int* __restrict__ deg, const int* __restrict__ bsum,
                        int* __restrict__ rp, int* __restrict__ cursor,
                        float* __restrict__ invd, int n) {
    __shared__ int buf[2][256];
    int t = threadIdx.x;
    int i = blockIdx.x * 256 + t;
    int v = (i < n) ? deg[i] : 0;
    buf[0][t] = v;
    __syncthreads();
    int sel = 0;
    for (int off = 1; off < 256; off <<= 1) {
        int x = buf[sel][t];
        if (t >= off) x += buf[sel][t - off];
        buf[sel ^ 1][t] = x;
        sel ^= 1;
        __syncthreads();
    }
    int incl = buf[sel][t];
    int excl = incl - v;
    if (i < n) {
        int base = bsum[blockIdx.x];
        rp[i] = base + excl;
        cursor[i] = base + excl;
        invd[i] = 1.0f / fmaxf((float)v, 1.0f);
        if (i == n - 1) rp[n] = base + incl;  // == E
    }
}

// bucket fill: csr_col[pos] = col[e]
__global__ void k_fill(const int* __restrict__ row, const int* __restrict__ col,
                       int* __restrict__ cursor, int* __restrict__ ci, int e) {
    int i = blockIdx.x * 256 + threadIdx.x;
    if (i < e) {
        int p = atomicAdd(&cursor[row[i]], 1);
        ci[p] = col[i];
    }
}

// ---------------------------------------------------------------------------
// Fused SAGE aggregation over PROJECTED features (d=128 fixed):
//   OUT[node] = T[node] + invd[node] * sum_{nbr in CSR} P[nbr]
// One 32-lane half-wave per node, float4 per lane (512B coalesced row reads),
// 2-neighbor unroll with dual accumulators for memory-level parallelism.
__global__ __launch_bounds__(256) void k_agg2(const float* __restrict__ P,
                                              const int* __restrict__ rp,
                                              const int* __restrict__ ci,
                                              const float* __restrict__ invd,
                                              const float* __restrict__ T,
                                              float* __restrict__ OUT, int n) {
    int node = blockIdx.x * 8 + (threadIdx.x >> 5);
    if (node >= n) return;
    int lane = threadIdx.x & 31;
    int s = rp[node], e = rp[node + 1];
    const float4* base = reinterpret_cast<const float4*>(P);
    float4 a0 = make_float4(0.f, 0.f, 0.f, 0.f);
    float4 a1 = make_float4(0.f, 0.f, 0.f, 0.f);
    int j = s;
    for (; j + 2 <= e; j += 2) {
        int n0 = ci[j], n1 = ci[j + 1];
        float4 v0 = base[(size_t)n0 * 32 + lane];
        float4 v1 = base[(size_t)n1 * 32 + lane];
        a0.x += v0.x; a0.y += v0.y; a0.z += v0.z; a0.w += v0.w;
        a1.x += v1.x; a1.y += v1.y; a1.z += v1.z; a1.w += v1.w;
    }
    if (j < e) {
        int n0 = ci[j];
        float4 v0 = base[(size_t)n0 * 32 + lane];
        a0.x += v0.x; a0.y += v0.y; a0.z += v0.z; a0.w += v0.w;
    }
    float scl = invd[node];
    float4 t = reinterpret_cast<const float4*>(T)[(size_t)node * 32 + lane];
    float4 o;
    o.x = t.x + scl * (a0.x + a1.x);
    o.y = t.y + scl * (a0.y + a1.y);
    o.z = t.z + scl * (a0.z + a1.z);
    o.w = t.w + scl * (a0.w + a1.w);
    reinterpret_cast<float4*>(OUT)[(size_t)node * 32 + lane] = o;
}

// ---------------------------------------------------------------------------
// Dual-source register-tiled GEMM, BN=128 fixed (output width always 128).
// C[r][c] = sum_k A1[r][k]*Wa[k][c] (k<K1)  +  sum_k A2[r][k]*Wb[k][c] (k<K2)
// EPI 0: C = val + (b1?b1[c]:0)
// EPI 1: gated skip + relu:  z=sigmoid(val+b1[c]+b2[c]); C=relu(z*A2 + (1-z)*A1)
// EPI 2: gated skip (no relu)
template <int K1, int K2, int EPI>
__global__ __launch_bounds__(256) void k_gemm(const float* __restrict__ A1,
                                              const float* __restrict__ A2,
                                              const float* __restrict__ Wa,
                                              const float* __restrict__ Wb,
                                              const float* __restrict__ b1,
                                              const float* __restrict__ b2,
                                              float* __restrict__ C, int n) {
    constexpr int K = K1 + K2;
    constexpr int BM = 128, BK = 32;
    __shared__ float sA[BM][BK + 4];  // pad keeps float4 align + spreads banks
    __shared__ float sW[BK][128];

    const int tid = threadIdx.x;
    const int tx = tid & 15, ty = tid >> 4;
    const int row0 = blockIdx.x * BM;

    float acc[8][8];
#pragma unroll
    for (int m = 0; m < 8; ++m)
#pragma unroll
        for (int j = 0; j < 8; ++j) acc[m][j] = 0.0f;

    for (int kt = 0; kt < K / BK; ++kt) {
        const int kbase = kt * BK;
        const float* src;
        int stride, koff;
        if (kbase < K1) { src = A1; stride = K1; koff = kbase; }
        else            { src = A2; stride = K2; koff = kbase - K1; }

        // stage A tile: 128 rows x 32 cols = 1024 float4, 4 per thread
#pragma unroll
        for (int i = 0; i < 4; ++i) {
            int f = tid + i * 256;
            int r = f >> 3, c4 = (f & 7) << 2;
            float4 v = make_float4(0.f, 0.f, 0.f, 0.f);
            int gr = row0 + r;
            if (gr < n)
                v = *reinterpret_cast<const float4*>(src + (size_t)gr * stride + koff + c4);
            *reinterpret_cast<float4*>(&sA[r][c4]) = v;
        }
        // stage W tile: 32 rows x 128 cols = 1024 float4, 4 per thread
        const float* wsrc = (kbase < K1) ? (Wa + (size_t)kbase * 128)
                                         : (Wb + (size_t)(kbase - K1) * 128);
#pragma unroll
        for (int i = 0; i < 4; ++i) {
            int f = tid + i * 256;
            int r = f >> 5, c4 = (f & 31) << 2;
            *reinterpret_cast<float4*>(&sW[r][c4]) =
                *reinterpret_cast<const float4*>(wsrc + (size_t)r * 128 + c4);
        }
        __syncthreads();

#pragma unroll
        for (int k = 0; k < BK; ++k) {
            float a[8];
#pragma unroll
            for (int m = 0; m < 8; ++m) a[m] = sA[ty + 16 * m][k];
            float4 bv0 = *reinterpret_cast<const float4*>(&sW[k][4 * tx]);
            float4 bv1 = *reinterpret_cast<const float4*>(&sW[k][64 + 4 * tx]);
            float bj[8] = {bv0.x, bv0.y, bv0.z, bv0.w, bv1.x, bv1.y, bv1.z, bv1.w};
#pragma unroll
            for (int m = 0; m < 8; ++m)
#pragma unroll
                for (int j = 0; j < 8; ++j) acc[m][j] = fmaf(a[m], bj[j], acc[m][j]);
        }
        __syncthreads();
    }

    // epilogue
#pragma unroll
    for (int m = 0; m < 8; ++m) {
        int r = row0 + ty + 16 * m;
        if (r >= n) continue;
#pragma unroll
        for (int half = 0; half < 2; ++half) {
#pragma unroll
            for (int jj = 0; jj < 4; ++jj) {
                int j = half * 4 + jj;
                int c = half * 64 + 4 * tx + jj;
                float v = acc[m][j];
                if (EPI == 0) {
                    if (b1) v += b1[c];
                    C[(size_t)r * 128 + c] = v;
                } else {
                    v += b1[c] + b2[c];
                    float z = 1.0f / (1.0f + __expf(-v));
                    float o = A2[(size_t)r * 128 + c];
                    float s = A1[(size_t)r * 128 + c];
                    float out = z * o + (1.0f - z) * s;
                    if (EPI == 1) out = fmaxf(out, 0.0f);
                    C[(size_t)r * 128 + c] = out;
                }
            }
        }
    }
}

// ---------------------------------------------------------------------------
extern "C" void kernel_launch(void* const* d_in, const int* in_sizes, int n_in,
                              void* d_out, int out_size, void* d_ws, size_t ws_size,
                              hipStream_t stream) {
    const float* x    = (const float*)d_in[0];
    const int*   row  = (const int*)d_in[1];
    const int*   col  = (const int*)d_in[2];
    const float* W_sc = (const float*)d_in[3];
    const float* W_ci = (const float*)d_in[4];
    const float* b_ci = (const float*)d_in[5];
    const float* W_co = (const float*)d_in[6];
    const float* b_co = (const float*)d_in[7];
    const float* W0   = (const float*)d_in[8];
    const float* b0   = (const float*)d_in[9];
    const float* W1   = (const float*)d_in[10];
    const float* b1   = (const float*)d_in[11];
    const float* W2   = (const float*)d_in[12];
    const float* b2   = (const float*)d_in[13];
    const float* Wf   = (const float*)d_in[14];
    const float* bf   = (const float*)d_in[15];
    float* out = (float*)d_out;

    // workspace carve-up (all 256B aligned)
    char* p = (char*)d_ws;
    auto alloc = [&](size_t bytes) {
        char* q = p;
        p += (bytes + 255) & ~(size_t)255;
        return q;
    };
    int*   degi   = (int*)alloc(NN * 4);
    int*   rp     = (int*)alloc((NN + 1) * 4);
    int*   cursor = (int*)alloc(NN * 4);
    int*   bsum   = (int*)alloc(256 * 4);
    float* invd   = (float*)alloc(NN * 4);
    int*   ci     = (int*)alloc(EE * 4);
    float* P      = (float*)alloc((size_t)NN * 128 * 4);
    float* T      = (float*)alloc((size_t)NN * 128 * 4);
    float* sc     = (float*)alloc((size_t)NN * 128 * 4);
    float* t0     = (float*)alloc((size_t)NN * 128 * 4);
    float* t1     = (float*)alloc((size_t)NN * 128 * 4);

    const int NB_N  = (NN + 255) / 256;   // 196
    const int NB_E  = (EE + 255) / 256;   // 6250
    const int GB    = (NN + 127) / 128;   // 391 gemm row-blocks
    const int AGG_B = (NN + 7) / 8;       // 6250 blocks (8 half-waves/block)

    // ---- graph structure (rebuilt every call; ws is poisoned) ----
    k_zero_i32<<<NB_N, 256, 0, stream>>>(degi, NN);
    k_deg<<<NB_E, 256, 0, stream>>>(row, degi, EE);
    k_scan1<<<NB_N, 256, 0, stream>>>(degi, bsum, NN);
    k_scan2<<<1, 1, 0, stream>>>(bsum, NB_N);
    k_scan3<<<NB_N, 256, 0, stream>>>(degi, bsum, rp, cursor, invd, NN);
    k_fill<<<NB_E, 256, 0, stream>>>(row, col, cursor, ci, EE);

    // sc = x @ W_sc  (shared across all three gated skips)
    k_gemm<256, 0, 0><<<GB, 256, 0, stream>>>(x, nullptr, W_sc, nullptr,
                                              nullptr, nullptr, sc, NN);

    // ---- layer 0:  o1 = x@W0_top + b0 + Anorm@(x@W0_bot) ----
    k_gemm<256, 0, 0><<<GB, 256, 0, stream>>>(x, nullptr, W0 + 256 * 128, nullptr,
                                              nullptr, nullptr, P, NN);      // P0
    k_gemm<256, 0, 0><<<GB, 256, 0, stream>>>(x, nullptr, W0, nullptr,
                                              b0, nullptr, T, NN);           // T0
    k_agg2<<<AGG_B, 256, 0, stream>>>(P, rp, ci, invd, T, t0, NN);           // o1
    k_gemm<128, 128, 1><<<GB, 256, 0, stream>>>(sc, t0, W_ci, W_co,
                                                b_ci, b_co, t1, NN);         // o3

    // ---- layer 1 ----
    k_gemm<128, 0, 0><<<GB, 256, 0, stream>>>(t1, nullptr, W1 + 128 * 128, nullptr,
                                              nullptr, nullptr, P, NN);      // P1
    k_gemm<128, 0, 0><<<GB, 256, 0, stream>>>(t1, nullptr, W1, nullptr,
                                              b1, nullptr, T, NN);           // T1
    k_agg2<<<AGG_B, 256, 0, stream>>>(P, rp, ci, invd, T, t0, NN);           // o4
    k_gemm<128, 128, 1><<<GB, 256, 0, stream>>>(sc, t0, W_ci, W_co,
                                                b_ci, b_co, t1, NN);         // o6

    // ---- layer 2 ----
    k_gemm<128, 0, 0><<<GB, 256, 0, stream>>>(t1, nullptr, W2 + 128 * 128, nullptr,
                                              nullptr, nullptr, P, NN);      // P2
    k_gemm<128, 0, 0><<<GB, 256, 0, stream>>>(t1, nullptr, W2, nullptr,
                                              b2, nullptr, T, NN);           // T2
    k_agg2<<<AGG_B, 256, 0, stream>>>(P, rp, ci, invd, T, t0, NN);           // o7
    k_gemm<128, 128, 2><<<GB, 256, 0, stream>>>(sc, t0, W_ci, W_co,
                                                b_ci, b_co, t1, NN);         // o8

    // ---- classifier ----
    k_gemm<128, 0, 0><<<GB, 256, 0, stream>>>(t1, nullptr, Wf, nullptr,
                                              bf, nullptr, out, NN);
}

// Round 3
// 1126.708 us; speedup vs baseline: 1.2902x; 1.1475x over previous
//
#include <hip/hip_runtime.h>
#include <hip/hip_bf16.h>
#include <math.h>

// Problem constants (from reference)
#define NN 50000
#define EE 1600000
#define NFEAT 256
#define NHID 128
#define RNG 6250   // NN/8 — fill pass range
#define NPASS 8

// ---------------------------------------------------------------------------
__global__ void k_zero_i32(int* __restrict__ p, int n) {
    int i = blockIdx.x * 256 + threadIdx.x;
    if (i < n) p[i] = 0;
}

// slot-record pass: eslot[e] = position of edge within its destination bucket.
// After this pass cnt[] holds the degree histogram.
__global__ void k_slot(const int* __restrict__ row, int* __restrict__ cnt,
                       int* __restrict__ eslot, int e) {
    int i = blockIdx.x * 256 + threadIdx.x;
    if (i < e) eslot[i] = atomicAdd(&cnt[row[i]], 1);
}

// scan step 1: per-block (256-elem) sums
__global__ void k_scan1(const int* __restrict__ deg, int* __restrict__ bsum, int n) {
    __shared__ int s[256];
    int t = threadIdx.x;
    int i = blockIdx.x * 256 + t;
    s[t] = (i < n) ? deg[i] : 0;
    __syncthreads();
    for (int off = 128; off > 0; off >>= 1) {
        if (t < off) s[t] += s[t + off];
        __syncthreads();
    }
    if (t == 0) bsum[blockIdx.x] = s[0];
}

// scan step 2: serial exclusive scan of block sums (nb ~ 196, negligible)
__global__ void k_scan2(int* __restrict__ bsum, int nb) {
    if (blockIdx.x == 0 && threadIdx.x == 0) {
        int acc = 0;
        for (int i = 0; i < nb; ++i) { int t = bsum[i]; bsum[i] = acc; acc += t; }
    }
}

// scan step 3: full exclusive scan -> row_ptr; also inv_deg
__global__ void k_scan3(const int* __restrict__ deg, const int* __restrict__ bsum,
                        int* __restrict__ rp, float* __restrict__ invd, int n) {
    __shared__ int buf[2][256];
    int t = threadIdx.x;
    int i = blockIdx.x * 256 + t;
    int v = (i < n) ? deg[i] : 0;
    buf[0][t] = v;
    __syncthreads();
    int sel = 0;
    for (int off = 1; off < 256; off <<= 1) {
        int x = buf[sel][t];
        if (t >= off) x += buf[sel][t - off];
        buf[sel ^ 1][t] = x;
        sel ^= 1;
        __syncthreads();
    }
    int incl = buf[sel][t];
    int excl = incl - v;
    if (i < n) {
        int base = bsum[blockIdx.x];
        rp[i] = base + excl;
        invd[i] = 1.0f / fmaxf((float)v, 1.0f);
        if (i == n - 1) rp[n] = base + incl;  // == E
    }
}

// range-partitioned fill, no atomics. Pass y (blockIdx.y) writes only rows in
// [y*RNG, (y+1)*RNG) -> live ci window ~800KB stays L2-resident, lines are
// fully populated before eviction (kills the 64B partial-line amplification).
// Dispatch is x-major so passes execute approximately in sequence.
__global__ void k_fill8(const int* __restrict__ row, const int* __restrict__ col,
                        const int* __restrict__ eslot, const int* __restrict__ rp,
                        int* __restrict__ ci, int e) {
    int i = blockIdx.x * 256 + threadIdx.x;
    if (i >= e) return;
    int r = row[i];
    int lo = blockIdx.y * RNG;
    if (r >= lo && r < lo + RNG) ci[rp[r] + eslot[i]] = col[i];
}

// ---------------------------------------------------------------------------
// Fused SAGE aggregation over PROJECTED features (d=128 fixed):
//   OUT[node] = T[node] + invd[node] * sum_{nbr in CSR} P[nbr]
// One 32-lane half-wave per node, float4 per lane, 4-deep unrolled gather.
__global__ __launch_bounds__(256) void k_agg2(const float* __restrict__ P,
                                              const int* __restrict__ rp,
                                              const int* __restrict__ ci,
                                              const float* __restrict__ invd,
                                              const float* __restrict__ T,
                                              float* __restrict__ OUT, int n) {
    int node = blockIdx.x * 8 + (threadIdx.x >> 5);
    if (node >= n) return;
    int lane = threadIdx.x & 31;
    int s = rp[node], e = rp[node + 1];
    const float4* base = reinterpret_cast<const float4*>(P);
    float4 a0 = make_float4(0.f, 0.f, 0.f, 0.f);
    float4 a1 = make_float4(0.f, 0.f, 0.f, 0.f);
    float4 a2 = make_float4(0.f, 0.f, 0.f, 0.f);
    float4 a3 = make_float4(0.f, 0.f, 0.f, 0.f);
    int j = s;
    for (; j + 4 <= e; j += 4) {
        int n0 = ci[j], n1 = ci[j + 1], n2 = ci[j + 2], n3 = ci[j + 3];
        float4 v0 = base[(size_t)n0 * 32 + lane];
        float4 v1 = base[(size_t)n1 * 32 + lane];
        float4 v2 = base[(size_t)n2 * 32 + lane];
        float4 v3 = base[(size_t)n3 * 32 + lane];
        a0.x += v0.x; a0.y += v0.y; a0.z += v0.z; a0.w += v0.w;
        a1.x += v1.x; a1.y += v1.y; a1.z += v1.z; a1.w += v1.w;
        a2.x += v2.x; a2.y += v2.y; a2.z += v2.z; a2.w += v2.w;
        a3.x += v3.x; a3.y += v3.y; a3.z += v3.z; a3.w += v3.w;
    }
    for (; j < e; ++j) {
        int n0 = ci[j];
        float4 v0 = base[(size_t)n0 * 32 + lane];
        a0.x += v0.x; a0.y += v0.y; a0.z += v0.z; a0.w += v0.w;
    }
    float scl = invd[node];
    float4 t = reinterpret_cast<const float4*>(T)[(size_t)node * 32 + lane];
    float4 o;
    o.x = t.x + scl * ((a0.x + a1.x) + (a2.x + a3.x));
    o.y = t.y + scl * ((a0.y + a1.y) + (a2.y + a3.y));
    o.z = t.z + scl * ((a0.z + a1.z) + (a2.z + a3.z));
    o.w = t.w + scl * ((a0.w + a1.w) + (a2.w + a3.w));
    reinterpret_cast<float4*>(OUT)[(size_t)node * 32 + lane] = o;
}

// ---------------------------------------------------------------------------
// Multi-output register-tiled GEMM (single A source, up to 3 weight/output
// pairs selected by blockIdx.y; only y==0 gets a bias). BN=128 fixed.
template <int K, int NW>
__global__ __launch_bounds__(256) void k_gemmM(const float* __restrict__ A,
                                               const float* __restrict__ Wp0,
                                               const float* __restrict__ Wp1,
                                               const float* __restrict__ Wp2,
                                               const float* __restrict__ bias0,
                                               float* __restrict__ C0,
                                               float* __restrict__ C1,
                                               float* __restrict__ C2, int n) {
    constexpr int BM = 128, BK = 32;
    __shared__ float sA[BM][BK + 4];
    __shared__ float sW[BK][128];

    const float* W = Wp0;
    const float* bias = bias0;
    float* C = C0;
    if (NW > 1 && blockIdx.y == 1) { W = Wp1; bias = nullptr; C = C1; }
    if (NW > 2 && blockIdx.y == 2) { W = Wp2; bias = nullptr; C = C2; }

    const int tid = threadIdx.x;
    const int tx = tid & 15, ty = tid >> 4;
    const int row0 = blockIdx.x * BM;

    float acc[8][8];
#pragma unroll
    for (int m = 0; m < 8; ++m)
#pragma unroll
        for (int j = 0; j < 8; ++j) acc[m][j] = 0.0f;

    for (int kt = 0; kt < K / BK; ++kt) {
        const int kbase = kt * BK;
#pragma unroll
        for (int i = 0; i < 4; ++i) {
            int f = tid + i * 256;
            int r = f >> 3, c4 = (f & 7) << 2;
            float4 v = make_float4(0.f, 0.f, 0.f, 0.f);
            int gr = row0 + r;
            if (gr < n)
                v = *reinterpret_cast<const float4*>(A + (size_t)gr * K + kbase + c4);
            *reinterpret_cast<float4*>(&sA[r][c4]) = v;
        }
        const float* wsrc = W + (size_t)kbase * 128;
#pragma unroll
        for (int i = 0; i < 4; ++i) {
            int f = tid + i * 256;
            int r = f >> 5, c4 = (f & 31) << 2;
            *reinterpret_cast<float4*>(&sW[r][c4]) =
                *reinterpret_cast<const float4*>(wsrc + (size_t)r * 128 + c4);
        }
        __syncthreads();

#pragma unroll
        for (int k = 0; k < BK; ++k) {
            float a[8];
#pragma unroll
            for (int m = 0; m < 8; ++m) a[m] = sA[ty + 16 * m][k];
            float4 bv0 = *reinterpret_cast<const float4*>(&sW[k][4 * tx]);
            float4 bv1 = *reinterpret_cast<const float4*>(&sW[k][64 + 4 * tx]);
            float bj[8] = {bv0.x, bv0.y, bv0.z, bv0.w, bv1.x, bv1.y, bv1.z, bv1.w};
#pragma unroll
            for (int m = 0; m < 8; ++m)
#pragma unroll
                for (int j = 0; j < 8; ++j) acc[m][j] = fmaf(a[m], bj[j], acc[m][j]);
        }
        __syncthreads();
    }

#pragma unroll
    for (int m = 0; m < 8; ++m) {
        int r = row0 + ty + 16 * m;
        if (r >= n) continue;
#pragma unroll
        for (int half = 0; half < 2; ++half) {
#pragma unroll
            for (int jj = 0; jj < 4; ++jj) {
                int j = half * 4 + jj;
                int c = half * 64 + 4 * tx + jj;
                float v = acc[m][j];
                if (bias) v += bias[c];
                C[(size_t)r * 128 + c] = v;
            }
        }
    }
}

// ---------------------------------------------------------------------------
// Dual-source GEMM with gated-skip epilogue.
// EPI 1: z=sigmoid(val+b1+b2); C=relu(z*A2 + (1-z)*A1)
// EPI 2: same, no relu
template <int K1, int K2, int EPI>
__global__ __launch_bounds__(256) void k_gemm(const float* __restrict__ A1,
                                              const float* __restrict__ A2,
                                              const float* __restrict__ Wa,
                                              const float* __restrict__ Wb,
                                              const float* __restrict__ b1,
                                              const float* __restrict__ b2,
                                              float* __restrict__ C, int n) {
    constexpr int K = K1 + K2;
    constexpr int BM = 128, BK = 32;
    __shared__ float sA[BM][BK + 4];
    __shared__ float sW[BK][128];

    const int tid = threadIdx.x;
    const int tx = tid & 15, ty = tid >> 4;
    const int row0 = blockIdx.x * BM;

    float acc[8][8];
#pragma unroll
    for (int m = 0; m < 8; ++m)
#pragma unroll
        for (int j = 0; j < 8; ++j) acc[m][j] = 0.0f;

    for (int kt = 0; kt < K / BK; ++kt) {
        const int kbase = kt * BK;
        const float* src;
        int stride, koff;
        if (kbase < K1) { src = A1; stride = K1; koff = kbase; }
        else            { src = A2; stride = K2; koff = kbase - K1; }

#pragma unroll
        for (int i = 0; i < 4; ++i) {
            int f = tid + i * 256;
            int r = f >> 3, c4 = (f & 7) << 2;
            float4 v = make_float4(0.f, 0.f, 0.f, 0.f);
            int gr = row0 + r;
            if (gr < n)
                v = *reinterpret_cast<const float4*>(src + (size_t)gr * stride + koff + c4);
            *reinterpret_cast<float4*>(&sA[r][c4]) = v;
        }
        const float* wsrc = (kbase < K1) ? (Wa + (size_t)kbase * 128)
                                         : (Wb + (size_t)(kbase - K1) * 128);
#pragma unroll
        for (int i = 0; i < 4; ++i) {
            int f = tid + i * 256;
            int r = f >> 5, c4 = (f & 31) << 2;
            *reinterpret_cast<float4*>(&sW[r][c4]) =
                *reinterpret_cast<const float4*>(wsrc + (size_t)r * 128 + c4);
        }
        __syncthreads();

#pragma unroll
        for (int k = 0; k < BK; ++k) {
            float a[8];
#pragma unroll
            for (int m = 0; m < 8; ++m) a[m] = sA[ty + 16 * m][k];
            float4 bv0 = *reinterpret_cast<const float4*>(&sW[k][4 * tx]);
            float4 bv1 = *reinterpret_cast<const float4*>(&sW[k][64 + 4 * tx]);
            float bj[8] = {bv0.x, bv0.y, bv0.z, bv0.w, bv1.x, bv1.y, bv1.z, bv1.w};
#pragma unroll
            for (int m = 0; m < 8; ++m)
#pragma unroll
                for (int j = 0; j < 8; ++j) acc[m][j] = fmaf(a[m], bj[j], acc[m][j]);
        }
        __syncthreads();
    }

#pragma unroll
    for (int m = 0; m < 8; ++m) {
        int r = row0 + ty + 16 * m;
        if (r >= n) continue;
#pragma unroll
        for (int half = 0; half < 2; ++half) {
#pragma unroll
            for (int jj = 0; jj < 4; ++jj) {
                int j = half * 4 + jj;
                int c = half * 64 + 4 * tx + jj;
                float v = acc[m][j] + b1[c] + b2[c];
                float z = 1.0f / (1.0f + __expf(-v));
                float o = A2[(size_t)r * 128 + c];
                float s = A1[(size_t)r * 128 + c];
                float out = z * o + (1.0f - z) * s;
                if (EPI == 1) out = fmaxf(out, 0.0f);
                C[(size_t)r * 128 + c] = out;
            }
        }
    }
}

// ---------------------------------------------------------------------------
extern "C" void kernel_launch(void* const* d_in, const int* in_sizes, int n_in,
                              void* d_out, int out_size, void* d_ws, size_t ws_size,
                              hipStream_t stream) {
    const float* x    = (const float*)d_in[0];
    const int*   row  = (const int*)d_in[1];
    const int*   col  = (const int*)d_in[2];
    const float* W_sc = (const float*)d_in[3];
    const float* W_ci = (const float*)d_in[4];
    const float* b_ci = (const float*)d_in[5];
    const float* W_co = (const float*)d_in[6];
    const float* b_co = (const float*)d_in[7];
    const float* W0   = (const float*)d_in[8];
    const float* b0   = (const float*)d_in[9];
    const float* W1   = (const float*)d_in[10];
    const float* b1   = (const float*)d_in[11];
    const float* W2   = (const float*)d_in[12];
    const float* b2   = (const float*)d_in[13];
    const float* Wf   = (const float*)d_in[14];
    const float* bf   = (const float*)d_in[15];
    float* out = (float*)d_out;

    // workspace carve-up (all 256B aligned)
    char* p = (char*)d_ws;
    auto alloc = [&](size_t bytes) {
        char* q = p;
        p += (bytes + 255) & ~(size_t)255;
        return q;
    };
    int*   cnt   = (int*)alloc(NN * 4);
    int*   rp    = (int*)alloc((NN + 1) * 4);
    int*   bsum  = (int*)alloc(256 * 4);
    float* invd  = (float*)alloc(NN * 4);
    int*   ci    = (int*)alloc(EE * 4);
    int*   eslot = (int*)alloc(EE * 4);
    float* P     = (float*)alloc((size_t)NN * 128 * 4);
    float* T     = (float*)alloc((size_t)NN * 128 * 4);
    float* sc    = (float*)alloc((size_t)NN * 128 * 4);
    float* t0    = (float*)alloc((size_t)NN * 128 * 4);
    float* t1    = (float*)alloc((size_t)NN * 128 * 4);

    const int NB_N  = (NN + 255) / 256;   // 196
    const int NB_E  = (EE + 255) / 256;   // 6250
    const int GB    = (NN + 127) / 128;   // 391 gemm row-blocks
    const int AGG_B = (NN + 7) / 8;       // 6250 blocks (8 half-waves/block)

    // ---- graph structure (rebuilt every call; ws is poisoned) ----
    k_zero_i32<<<NB_N, 256, 0, stream>>>(cnt, NN);
    k_slot<<<NB_E, 256, 0, stream>>>(row, cnt, eslot, EE);
    k_scan1<<<NB_N, 256, 0, stream>>>(cnt, bsum, NN);
    k_scan2<<<1, 1, 0, stream>>>(bsum, NB_N);
    k_scan3<<<NB_N, 256, 0, stream>>>(cnt, bsum, rp, invd, NN);
    k_fill8<<<dim3(NB_E, NPASS), 256, 0, stream>>>(row, col, eslot, rp, ci, EE);

    // ---- layer 0:  T0 = x@W0_top + b0,  P0 = x@W0_bot,  sc = x@W_sc ----
    k_gemmM<256, 3><<<dim3(GB, 3), 256, 0, stream>>>(x, W0, W0 + 256 * 128, W_sc,
                                                     b0, T, P, sc, NN);
    k_agg2<<<AGG_B, 256, 0, stream>>>(P, rp, ci, invd, T, t0, NN);           // o1
    k_gemm<128, 128, 1><<<GB, 256, 0, stream>>>(sc, t0, W_ci, W_co,
                                                b_ci, b_co, t1, NN);         // o3

    // ---- layer 1 ----
    k_gemmM<128, 2><<<dim3(GB, 2), 256, 0, stream>>>(t1, W1, W1 + 128 * 128, nullptr,
                                                     b1, T, P, nullptr, NN);
    k_agg2<<<AGG_B, 256, 0, stream>>>(P, rp, ci, invd, T, t0, NN);           // o4
    k_gemm<128, 128, 1><<<GB, 256, 0, stream>>>(sc, t0, W_ci, W_co,
                                                b_ci, b_co, t1, NN);         // o6

    // ---- layer 2 ----
    k_gemmM<128, 2><<<dim3(GB, 2), 256, 0, stream>>>(t1, W2, W2 + 128 * 128, nullptr,
                                                     b2, T, P, nullptr, NN);
    k_agg2<<<AGG_B, 256, 0, stream>>>(P, rp, ci, invd, T, t0, NN);           // o7
    k_gemm<128, 128, 2><<<GB, 256, 0, stream>>>(sc, t0, W_ci, W_co,
                                                b_ci, b_co, t1, NN);         // o8

    // ---- classifier ----
    k_gemmM<128, 1><<<GB, 256, 0, stream>>>(t1, Wf, nullptr, nullptr,
                                            bf, out, nullptr, nullptr, NN);
}

// Round 4
// 560.337 us; speedup vs baseline: 2.5944x; 2.0108x over previous
//
#include <hip/hip_runtime.h>
#include <hip/hip_bf16.h>
#include <hip/hip_fp16.h>
#include <math.h>

// Problem constants (from reference)
#define NN 50000
#define EE 1600000
#define NFEAT 256
#define NHID 128
#define RNG 6250   // NN/8 — fill pass range
#define NPASS 8

typedef _Float16 f16;
typedef _Float16 f16x8 __attribute__((ext_vector_type(8)));
typedef _Float16 f16x4 __attribute__((ext_vector_type(4)));
typedef float f32x4 __attribute__((ext_vector_type(4)));

// ---------------------------------------------------------------------------
__global__ void k_zero_i32(int* __restrict__ p, int n) {
    int i = blockIdx.x * 256 + threadIdx.x;
    if (i < n) p[i] = 0;
}

// slot-record pass: eslot[e] = position of edge within its destination bucket.
// After this pass cnt[] holds the degree histogram.
__global__ void k_slot(const int* __restrict__ row, int* __restrict__ cnt,
                       int* __restrict__ eslot, int e) {
    int i = blockIdx.x * 256 + threadIdx.x;
    if (i < e) eslot[i] = atomicAdd(&cnt[row[i]], 1);
}

__global__ void k_scan1(const int* __restrict__ deg, int* __restrict__ bsum, int n) {
    __shared__ int s[256];
    int t = threadIdx.x;
    int i = blockIdx.x * 256 + t;
    s[t] = (i < n) ? deg[i] : 0;
    __syncthreads();
    for (int off = 128; off > 0; off >>= 1) {
        if (t < off) s[t] += s[t + off];
        __syncthreads();
    }
    if (t == 0) bsum[blockIdx.x] = s[0];
}

__global__ void k_scan2(int* __restrict__ bsum, int nb) {
    if (blockIdx.x == 0 && threadIdx.x == 0) {
        int acc = 0;
        for (int i = 0; i < nb; ++i) { int t = bsum[i]; bsum[i] = acc; acc += t; }
    }
}

__global__ void k_scan3(const int* __restrict__ deg, const int* __restrict__ bsum,
                        int* __restrict__ rp, float* __restrict__ invd, int n) {
    __shared__ int buf[2][256];
    int t = threadIdx.x;
    int i = blockIdx.x * 256 + t;
    int v = (i < n) ? deg[i] : 0;
    buf[0][t] = v;
    __syncthreads();
    int sel = 0;
    for (int off = 1; off < 256; off <<= 1) {
        int x = buf[sel][t];
        if (t >= off) x += buf[sel][t - off];
        buf[sel ^ 1][t] = x;
        sel ^= 1;
        __syncthreads();
    }
    int incl = buf[sel][t];
    int excl = incl - v;
    if (i < n) {
        int base = bsum[blockIdx.x];
        rp[i] = base + excl;
        invd[i] = 1.0f / fmaxf((float)v, 1.0f);
        if (i == n - 1) rp[n] = base + incl;  // == E
    }
}

// range-partitioned fill, no atomics (live ci window stays L2-resident).
__global__ void k_fill8(const int* __restrict__ row, const int* __restrict__ col,
                        const int* __restrict__ eslot, const int* __restrict__ rp,
                        int* __restrict__ ci, int e) {
    int i = blockIdx.x * 256 + threadIdx.x;
    if (i >= e) return;
    int r = row[i];
    int lo = blockIdx.y * RNG;
    if (r >= lo && r < lo + RNG) ci[rp[r] + eslot[i]] = col[i];
}

// ---------------------------------------------------------------------------
// fp32 -> fp16 convert (x), float4 granularity
__global__ void k_cvt_x(const float* __restrict__ src, f16* __restrict__ dst, int n4) {
    int i = blockIdx.x * 256 + threadIdx.x;
    if (i >= n4) return;
    float4 v = reinterpret_cast<const float4*>(src)[i];
    f16x4 h = {(f16)v.x, (f16)v.y, (f16)v.z, (f16)v.w};
    reinterpret_cast<f16x4*>(dst)[i] = h;
}

// weight convert + transpose: src [K x 128] fp32 row-major -> dst [128 x K] fp16
struct WD { const float* s; f16* d; int K; };
struct WDs { WD w[10]; };
__global__ void k_cvtW(WDs ds) {
    WD w = ds.w[blockIdx.y];
    int total = w.K * 128;
    for (int idx = blockIdx.x * 256 + threadIdx.x; idx < total; idx += gridDim.x * 256) {
        int k = idx >> 7, c = idx & 127;
        w.d[c * w.K + k] = (f16)w.s[idx];
    }
}

// ---------------------------------------------------------------------------
// Fused SAGE aggregation (fp16 features, d=128):
//   OUT[node] = T[node] + invd[node] * sum_{nbr} P[nbr]
// 16 lanes per node, 16B (8 halves) per lane, 4-deep unrolled gather, fp32 accum.
__global__ __launch_bounds__(256) void k_agg2h(const f16* __restrict__ P,
                                               const int* __restrict__ rp,
                                               const int* __restrict__ ci,
                                               const float* __restrict__ invd,
                                               const f16* __restrict__ T,
                                               f16* __restrict__ OUT, int n) {
    int node = blockIdx.x * 16 + (threadIdx.x >> 4);
    if (node >= n) return;
    int lane = threadIdx.x & 15;
    int s = rp[node], e = rp[node + 1];
    float acc[8];
#pragma unroll
    for (int q = 0; q < 8; ++q) acc[q] = 0.0f;
    int j = s;
    for (; j + 4 <= e; j += 4) {
        int n0 = ci[j], n1 = ci[j + 1], n2 = ci[j + 2], n3 = ci[j + 3];
        f16x8 v0 = *reinterpret_cast<const f16x8*>(P + (size_t)n0 * 128 + lane * 8);
        f16x8 v1 = *reinterpret_cast<const f16x8*>(P + (size_t)n1 * 128 + lane * 8);
        f16x8 v2 = *reinterpret_cast<const f16x8*>(P + (size_t)n2 * 128 + lane * 8);
        f16x8 v3 = *reinterpret_cast<const f16x8*>(P + (size_t)n3 * 128 + lane * 8);
#pragma unroll
        for (int q = 0; q < 8; ++q)
            acc[q] += ((float)v0[q] + (float)v1[q]) + ((float)v2[q] + (float)v3[q]);
    }
    for (; j < e; ++j) {
        f16x8 v0 = *reinterpret_cast<const f16x8*>(P + (size_t)ci[j] * 128 + lane * 8);
#pragma unroll
        for (int q = 0; q < 8; ++q) acc[q] += (float)v0[q];
    }
    float scl = invd[node];
    f16x8 tv = *reinterpret_cast<const f16x8*>(T + (size_t)node * 128 + lane * 8);
    f16x8 o;
#pragma unroll
    for (int q = 0; q < 8; ++q) o[q] = (f16)((float)tv[q] + scl * acc[q]);
    *reinterpret_cast<f16x8*>(OUT + (size_t)node * 128 + lane * 8) = o;
}

// ---------------------------------------------------------------------------
// MFMA fp16 GEMM building blocks.
// Tile: BM=64, BN=128, BK=32; 256 threads = 4 waves (2x2), wave tile 32x64.
// LDS: padded stride 40 halves (80B) -> conflict-free ds_read_b128 fragments.
// Fragment layout (gfx950 16x16x32): A: row=lane&15, k=(lane>>4)*8+j;
// B: col=lane&15, k=(lane>>4)*8+j; C/D: col=lane&15, row=(lane>>4)*4+reg.
#define LDSSTR 40

__device__ __forceinline__ void stage_A(const f16* __restrict__ A, f16* sA,
                                        int row0, int K, int kb, int tid, int n) {
    int r = tid >> 2, ch = tid & 3;
    int gr = row0 + r;
    uint4 v = make_uint4(0, 0, 0, 0);
    if (gr < n) v = *reinterpret_cast<const uint4*>(A + (size_t)gr * K + kb + ch * 8);
    *reinterpret_cast<uint4*>(sA + r * LDSSTR + ch * 8) = v;
}

__device__ __forceinline__ void stage_B(const f16* __restrict__ Wt, f16* sB,
                                        int K, int kb, int tid) {
    // 128 cols x 32 halves = 512 uint4 chunks, 2 per thread
#pragma unroll
    for (int i = 0; i < 2; ++i) {
        int idx = tid + i * 256;
        int c = idx >> 2, ch = idx & 3;
        uint4 v = *reinterpret_cast<const uint4*>(Wt + (size_t)c * K + kb + ch * 8);
        *reinterpret_cast<uint4*>(sB + c * LDSSTR + ch * 8) = v;
    }
}

// Multi-output MFMA GEMM: A [n x K] fp16, blockIdx.y selects (W,bias,C).
// Only y==0 applies bias0. F32OUT: write fp32 (classifier), else fp16.
template <int K, int NW, bool F32OUT>
__global__ __launch_bounds__(256) void k_mgemm(const f16* __restrict__ A,
                                               const f16* __restrict__ Wt0,
                                               const f16* __restrict__ Wt1,
                                               const f16* __restrict__ Wt2,
                                               const float* __restrict__ bias0,
                                               void* __restrict__ C0,
                                               void* __restrict__ C1,
                                               void* __restrict__ C2, int n) {
    __shared__ f16 sA[64 * LDSSTR];
    __shared__ f16 sB[128 * LDSSTR];

    const f16* Wt = Wt0;
    const float* bias = bias0;
    void* C = C0;
    if (NW > 1 && blockIdx.y == 1) { Wt = Wt1; bias = nullptr; C = C1; }
    if (NW > 2 && blockIdx.y == 2) { Wt = Wt2; bias = nullptr; C = C2; }

    const int tid = threadIdx.x;
    const int row0 = blockIdx.x * 64;
    const int wid = tid >> 6, l = tid & 63;
    const int wr = wid >> 1, wc = wid & 1;
    const int lr = l & 15, lk = (l >> 4) * 8;

    f32x4 acc[2][4];
#pragma unroll
    for (int m = 0; m < 2; ++m)
#pragma unroll
        for (int q = 0; q < 4; ++q) acc[m][q] = (f32x4){0.f, 0.f, 0.f, 0.f};

    for (int kt = 0; kt < K / 32; ++kt) {
        stage_A(A, sA, row0, K, kt * 32, tid, n);
        stage_B(Wt, sB, K, kt * 32, tid);
        __syncthreads();
        f16x8 aF[2], bF[4];
#pragma unroll
        for (int m = 0; m < 2; ++m)
            aF[m] = *reinterpret_cast<f16x8*>(sA + (wr * 32 + m * 16 + lr) * LDSSTR + lk);
#pragma unroll
        for (int q = 0; q < 4; ++q)
            bF[q] = *reinterpret_cast<f16x8*>(sB + (wc * 64 + q * 16 + lr) * LDSSTR + lk);
#pragma unroll
        for (int m = 0; m < 2; ++m)
#pragma unroll
            for (int q = 0; q < 4; ++q)
                acc[m][q] = __builtin_amdgcn_mfma_f32_16x16x32_f16(aF[m], bF[q],
                                                                   acc[m][q], 0, 0, 0);
        __syncthreads();
    }

    const int lr4 = (l >> 4) * 4;
#pragma unroll
    for (int m = 0; m < 2; ++m)
#pragma unroll
        for (int q = 0; q < 4; ++q) {
            int c = wc * 64 + q * 16 + (l & 15);
            float b = bias ? bias[c] : 0.0f;
#pragma unroll
            for (int reg = 0; reg < 4; ++reg) {
                int r = row0 + wr * 32 + m * 16 + lr4 + reg;
                if (r >= n) continue;
                float v = acc[m][q][reg] + b;
                if (F32OUT) ((float*)C)[(size_t)r * 128 + c] = v;
                else        ((f16*)C)[(size_t)r * 128 + c] = (f16)v;
            }
        }
}

// Gated-skip MFMA GEMM: G = sc@Wci + t0@Wco; z=sigmoid(G+bci+bco);
// out = z*t0 + (1-z)*sc, optional relu, fp16 out.
template <int RELU>
__global__ __launch_bounds__(256) void k_ggemm(const f16* __restrict__ Asc,
                                               const f16* __restrict__ At0,
                                               const f16* __restrict__ Wci,
                                               const f16* __restrict__ Wco,
                                               const float* __restrict__ bci,
                                               const float* __restrict__ bco,
                                               f16* __restrict__ C, int n) {
    __shared__ f16 sA[64 * LDSSTR];
    __shared__ f16 sB[128 * LDSSTR];

    const int tid = threadIdx.x;
    const int row0 = blockIdx.x * 64;
    const int wid = tid >> 6, l = tid & 63;
    const int wr = wid >> 1, wc = wid & 1;
    const int lr = l & 15, lk = (l >> 4) * 8;

    f32x4 acc[2][4];
#pragma unroll
    for (int m = 0; m < 2; ++m)
#pragma unroll
        for (int q = 0; q < 4; ++q) acc[m][q] = (f32x4){0.f, 0.f, 0.f, 0.f};

    for (int kt = 0; kt < 8; ++kt) {
        const f16* A = (kt < 4) ? Asc : At0;
        const f16* Wt = (kt < 4) ? Wci : Wco;
        int kb = (kt & 3) * 32;
        stage_A(A, sA, row0, 128, kb, tid, n);
        stage_B(Wt, sB, 128, kb, tid);
        __syncthreads();
        f16x8 aF[2], bF[4];
#pragma unroll
        for (int m = 0; m < 2; ++m)
            aF[m] = *reinterpret_cast<f16x8*>(sA + (wr * 32 + m * 16 + lr) * LDSSTR + lk);
#pragma unroll
        for (int q = 0; q < 4; ++q)
            bF[q] = *reinterpret_cast<f16x8*>(sB + (wc * 64 + q * 16 + lr) * LDSSTR + lk);
#pragma unroll
        for (int m = 0; m < 2; ++m)
#pragma unroll
            for (int q = 0; q < 4; ++q)
                acc[m][q] = __builtin_amdgcn_mfma_f32_16x16x32_f16(aF[m], bF[q],
                                                                   acc[m][q], 0, 0, 0);
        __syncthreads();
    }

    const int lr4 = (l >> 4) * 4;
#pragma unroll
    for (int m = 0; m < 2; ++m)
#pragma unroll
        for (int q = 0; q < 4; ++q) {
            int c = wc * 64 + q * 16 + (l & 15);
            float b = bci[c] + bco[c];
#pragma unroll
            for (int reg = 0; reg < 4; ++reg) {
                int r = row0 + wr * 32 + m * 16 + lr4 + reg;
                if (r >= n) continue;
                float v = acc[m][q][reg] + b;
                float z = 1.0f / (1.0f + __expf(-v));
                float o = (float)At0[(size_t)r * 128 + c];
                float s = (float)Asc[(size_t)r * 128 + c];
                float outv = z * o + (1.0f - z) * s;
                if (RELU) outv = fmaxf(outv, 0.0f);
                C[(size_t)r * 128 + c] = (f16)outv;
            }
        }
}

// ---------------------------------------------------------------------------
extern "C" void kernel_launch(void* const* d_in, const int* in_sizes, int n_in,
                              void* d_out, int out_size, void* d_ws, size_t ws_size,
                              hipStream_t stream) {
    const float* x    = (const float*)d_in[0];
    const int*   row  = (const int*)d_in[1];
    const int*   col  = (const int*)d_in[2];
    const float* W_sc = (const float*)d_in[3];
    const float* W_ci = (const float*)d_in[4];
    const float* b_ci = (const float*)d_in[5];
    const float* W_co = (const float*)d_in[6];
    const float* b_co = (const float*)d_in[7];
    const float* W0   = (const float*)d_in[8];
    const float* b0   = (const float*)d_in[9];
    const float* W1   = (const float*)d_in[10];
    const float* b1   = (const float*)d_in[11];
    const float* W2   = (const float*)d_in[12];
    const float* b2   = (const float*)d_in[13];
    const float* Wf   = (const float*)d_in[14];
    const float* bf   = (const float*)d_in[15];
    float* out = (float*)d_out;

    char* p = (char*)d_ws;
    auto alloc = [&](size_t bytes) {
        char* q = p;
        p += (bytes + 255) & ~(size_t)255;
        return q;
    };
    int*   cnt   = (int*)alloc(NN * 4);
    int*   rp    = (int*)alloc((NN + 1) * 4);
    int*   bsum  = (int*)alloc(256 * 4);
    float* invd  = (float*)alloc(NN * 4);
    int*   ci    = (int*)alloc(EE * 4);
    int*   eslot = (int*)alloc(EE * 4);
    f16*   x_h   = (f16*)alloc((size_t)NN * 256 * 2);
    f16*   sc_h  = (f16*)alloc((size_t)NN * 128 * 2);
    f16*   T_h   = (f16*)alloc((size_t)NN * 128 * 2);
    f16*   P_h   = (f16*)alloc((size_t)NN * 128 * 2);
    f16*   t0_h  = (f16*)alloc((size_t)NN * 128 * 2);
    f16*   t1_h  = (f16*)alloc((size_t)NN * 128 * 2);
    // transposed fp16 weights [128 x K]
    f16* W0t_t = (f16*)alloc(256 * 128 * 2);
    f16* W0b_t = (f16*)alloc(256 * 128 * 2);
    f16* Wsc_t = (f16*)alloc(256 * 128 * 2);
    f16* W1t_t = (f16*)alloc(128 * 128 * 2);
    f16* W1b_t = (f16*)alloc(128 * 128 * 2);
    f16* W2t_t = (f16*)alloc(128 * 128 * 2);
    f16* W2b_t = (f16*)alloc(128 * 128 * 2);
    f16* Wci_t = (f16*)alloc(128 * 128 * 2);
    f16* Wco_t = (f16*)alloc(128 * 128 * 2);
    f16* Wf_t  = (f16*)alloc(128 * 128 * 2);

    const int NB_N  = (NN + 255) / 256;   // 196
    const int NB_E  = (EE + 255) / 256;   // 6250
    const int GB    = (NN + 63) / 64;     // 782 mfma-gemm row-blocks
    const int AGG_B = (NN + 15) / 16;     // 3125 blocks (16 nodes/block)

    // ---- conversions (independent of graph build) ----
    k_cvt_x<<<(NN * 256 / 4 + 255) / 256, 256, 0, stream>>>(x, x_h, NN * 256 / 4);
    WDs ds;
    ds.w[0] = {W0, W0t_t, 256};
    ds.w[1] = {W0 + 256 * 128, W0b_t, 256};
    ds.w[2] = {W_sc, Wsc_t, 256};
    ds.w[3] = {W1, W1t_t, 128};
    ds.w[4] = {W1 + 128 * 128, W1b_t, 128};
    ds.w[5] = {W2, W2t_t, 128};
    ds.w[6] = {W2 + 128 * 128, W2b_t, 128};
    ds.w[7] = {W_ci, Wci_t, 128};
    ds.w[8] = {W_co, Wco_t, 128};
    ds.w[9] = {Wf, Wf_t, 128};
    k_cvtW<<<dim3(64, 10), 256, 0, stream>>>(ds);

    // ---- graph structure (rebuilt every call; ws is poisoned) ----
    k_zero_i32<<<NB_N, 256, 0, stream>>>(cnt, NN);
    k_slot<<<NB_E, 256, 0, stream>>>(row, cnt, eslot, EE);
    k_scan1<<<NB_N, 256, 0, stream>>>(cnt, bsum, NN);
    k_scan2<<<1, 1, 0, stream>>>(bsum, NB_N);
    k_scan3<<<NB_N, 256, 0, stream>>>(cnt, bsum, rp, invd, NN);
    k_fill8<<<dim3(NB_E, NPASS), 256, 0, stream>>>(row, col, eslot, rp, ci, EE);

    // ---- layer 0:  T = x@W0top + b0, P = x@W0bot, sc = x@W_sc ----
    k_mgemm<256, 3, false><<<dim3(GB, 3), 256, 0, stream>>>(
        x_h, W0t_t, W0b_t, Wsc_t, b0, T_h, P_h, sc_h, NN);
    k_agg2h<<<AGG_B, 256, 0, stream>>>(P_h, rp, ci, invd, T_h, t0_h, NN);    // o1
    k_ggemm<1><<<GB, 256, 0, stream>>>(sc_h, t0_h, Wci_t, Wco_t,
                                       b_ci, b_co, t1_h, NN);                // o3

    // ---- layer 1 ----
    k_mgemm<128, 2, false><<<dim3(GB, 2), 256, 0, stream>>>(
        t1_h, W1t_t, W1b_t, nullptr, b1, T_h, P_h, nullptr, NN);
    k_agg2h<<<AGG_B, 256, 0, stream>>>(P_h, rp, ci, invd, T_h, t0_h, NN);    // o4
    k_ggemm<1><<<GB, 256, 0, stream>>>(sc_h, t0_h, Wci_t, Wco_t,
                                       b_ci, b_co, t1_h, NN);                // o6

    // ---- layer 2 ----
    k_mgemm<128, 2, false><<<dim3(GB, 2), 256, 0, stream>>>(
        t1_h, W2t_t, W2b_t, nullptr, b2, T_h, P_h, nullptr, NN);
    k_agg2h<<<AGG_B, 256, 0, stream>>>(P_h, rp, ci, invd, T_h, t0_h, NN);    // o7
    k_ggemm<0><<<GB, 256, 0, stream>>>(sc_h, t0_h, Wci_t, Wco_t,
                                       b_ci, b_co, t1_h, NN);                // o8

    // ---- classifier: out = t1 @ Wf + bf (fp32 out) ----
    k_mgemm<128, 1, true><<<GB, 256, 0, stream>>>(
        t1_h, Wf_t, nullptr, nullptr, bf, out, nullptr, nullptr, NN);
}

// Round 6
// 541.806 us; speedup vs baseline: 2.6831x; 1.0342x over previous
//
#include <hip/hip_runtime.h>
#include <hip/hip_bf16.h>
#include <hip/hip_fp16.h>
#include <math.h>

// Problem constants (from reference)
#define NN 50000
#define EE 1600000
#define NFEAT 256
#define NHID 128
#define RNG 6250   // NN/8 — fill pass range
#define NPASS 8
#define CPAD 16    // counter padding: one counter per 64B line

typedef _Float16 f16;
typedef _Float16 f16x8 __attribute__((ext_vector_type(8)));
typedef _Float16 f16x4 __attribute__((ext_vector_type(4)));
typedef float f32x4 __attribute__((ext_vector_type(4)));

// ---------------------------------------------------------------------------
// Combined prep: fp32->fp16 convert of x, zero padded counters, convert+
// transpose all weights. One dispatch, block ranges keep each part coalesced.
struct WPtrs {
    const float* s[10];
    f16* d[10];
};

__global__ __launch_bounds__(256) void k_prep(const float* __restrict__ x,
                                              f16* __restrict__ xh, int n4,
                                              int* __restrict__ cnt, int nz4,
                                              WPtrs wp, int wtotal,
                                              int zb0, int wb0, int wblocks) {
    int b = blockIdx.x;
    if (b < zb0) {
        int i = b * 256 + threadIdx.x;
        if (i < n4) {
            float4 v = reinterpret_cast<const float4*>(x)[i];
            f16x4 h = {(f16)v.x, (f16)v.y, (f16)v.z, (f16)v.w};
            reinterpret_cast<f16x4*>(xh)[i] = h;
        }
    } else if (b < wb0) {
        int i = (b - zb0) * 256 + threadIdx.x;
        if (i < nz4) reinterpret_cast<int4*>(cnt)[i] = make_int4(0, 0, 0, 0);
    } else {
        for (int idx = (b - wb0) * 256 + threadIdx.x; idx < wtotal;
             idx += wblocks * 256) {
            int wsel, rem, K;
            if (idx < 3 * 32768) { wsel = idx >> 15; rem = idx & 32767; K = 256; }
            else { int t = idx - 3 * 32768; wsel = 3 + (t >> 14); rem = t & 16383; K = 128; }
            int k = rem >> 7, c = rem & 127;
            wp.d[wsel][c * K + k] = (f16)wp.s[wsel][rem];
        }
    }
}

// slot-record pass: eslot[e] = position of edge within its destination bucket.
// Counters padded to one per 64B line -> 32 atomics/line instead of 512.
__global__ void k_slot(const int* __restrict__ row, int* __restrict__ cnt,
                       int* __restrict__ eslot, int e) {
    int i = blockIdx.x * 256 + threadIdx.x;
    if (i < e) eslot[i] = atomicAdd(&cnt[(size_t)row[i] * CPAD], 1);
}

// scan step 1: per-block (256-elem) sums of padded counters
__global__ void k_scan1(const int* __restrict__ cnt, int* __restrict__ bsum, int n) {
    __shared__ int s[256];
    int t = threadIdx.x;
    int i = blockIdx.x * 256 + t;
    s[t] = (i < n) ? cnt[(size_t)i * CPAD] : 0;
    __syncthreads();
    for (int off = 128; off > 0; off >>= 1) {
        if (t < off) s[t] += s[t + off];
        __syncthreads();
    }
    if (t == 0) bsum[blockIdx.x] = s[0];
}

// scan step 2+3 fused: each block scans the block sums itself (nb<=256),
// then does its 256-element exclusive scan -> rp, invd.
__global__ void k_scan3(const int* __restrict__ cnt, const int* __restrict__ bsum,
                        int* __restrict__ rp, float* __restrict__ invd,
                        int n, int nb) {
    __shared__ int buf[2][256];
    __shared__ int bpre[2][256];
    int t = threadIdx.x;

    // scan block sums (inclusive) in LDS, double-buffered
    bpre[0][t] = (t < nb) ? bsum[t] : 0;
    __syncthreads();
    int bs = 0;
    for (int off = 1; off < 256; off <<= 1) {
        int v = bpre[bs][t];
        if (t >= off) v += bpre[bs][t - off];
        bpre[bs ^ 1][t] = v;
        bs ^= 1;
        __syncthreads();
    }
    int base = (blockIdx.x == 0) ? 0 : bpre[bs][blockIdx.x - 1];

    int i = blockIdx.x * 256 + t;
    int v = (i < n) ? cnt[(size_t)i * CPAD] : 0;
    buf[0][t] = v;
    __syncthreads();
    int sel = 0;
    for (int off = 1; off < 256; off <<= 1) {
        int x = buf[sel][t];
        if (t >= off) x += buf[sel][t - off];
        buf[sel ^ 1][t] = x;
        sel ^= 1;
        __syncthreads();
    }
    int incl = buf[sel][t];
    int excl = incl - v;
    if (i < n) {
        rp[i] = base + excl;
        invd[i] = 1.0f / fmaxf((float)v, 1.0f);
        if (i == n - 1) rp[n] = base + incl;  // == E
    }
}

// range-partitioned fill, no atomics (live ci window stays L2-resident).
__global__ void k_fill8(const int* __restrict__ row, const int* __restrict__ col,
                        const int* __restrict__ eslot, const int* __restrict__ rp,
                        int* __restrict__ ci, int e) {
    int i = blockIdx.x * 256 + threadIdx.x;
    if (i >= e) return;
    int r = row[i];
    int lo = blockIdx.y * RNG;
    if (r >= lo && r < lo + RNG) ci[rp[r] + eslot[i]] = col[i];
}

// ---------------------------------------------------------------------------
// Fused SAGE aggregation (fp16 features, d=128):
//   OUT[node] = T[node] + invd[node] * sum_{nbr} P[nbr]
// 16 lanes per node, 16B per lane, 8-deep unrolled gather, fp32 accum.
__global__ __launch_bounds__(256) void k_agg2h(const f16* __restrict__ P,
                                               const int* __restrict__ rp,
                                               const int* __restrict__ ci,
                                               const float* __restrict__ invd,
                                               const f16* __restrict__ T,
                                               f16* __restrict__ OUT, int n) {
    int node = blockIdx.x * 16 + (threadIdx.x >> 4);
    if (node >= n) return;
    int lane = threadIdx.x & 15;
    int s = rp[node], e = rp[node + 1];
    float acc[8];
#pragma unroll
    for (int q = 0; q < 8; ++q) acc[q] = 0.0f;
    int j = s;
    for (; j + 8 <= e; j += 8) {
        f16x8 v[8];
#pragma unroll
        for (int u = 0; u < 8; ++u)
            v[u] = *reinterpret_cast<const f16x8*>(P + (size_t)ci[j + u] * 128 + lane * 8);
#pragma unroll
        for (int q = 0; q < 8; ++q)
            acc[q] += (((float)v[0][q] + (float)v[1][q]) + ((float)v[2][q] + (float)v[3][q])) +
                      (((float)v[4][q] + (float)v[5][q]) + ((float)v[6][q] + (float)v[7][q]));
    }
    for (; j < e; ++j) {
        f16x8 v0 = *reinterpret_cast<const f16x8*>(P + (size_t)ci[j] * 128 + lane * 8);
#pragma unroll
        for (int q = 0; q < 8; ++q) acc[q] += (float)v0[q];
    }
    float scl = invd[node];
    f16x8 tv = *reinterpret_cast<const f16x8*>(T + (size_t)node * 128 + lane * 8);
    f16x8 o;
#pragma unroll
    for (int q = 0; q < 8; ++q) o[q] = (f16)((float)tv[q] + scl * acc[q]);
    *reinterpret_cast<f16x8*>(OUT + (size_t)node * 128 + lane * 8) = o;
}

// ---------------------------------------------------------------------------
// MFMA fp16 GEMM building blocks.
// Tile: BM=64, BN=128, BK=32; 256 threads = 4 waves (2x2), wave tile 32x64.
// LDS: padded stride 40 halves (80B) -> conflict-free ds_read_b128 fragments.
#define LDSSTR 40

__device__ __forceinline__ void stage_A(const f16* __restrict__ A, f16* sA,
                                        int row0, int K, int kb, int tid, int n) {
    int r = tid >> 2, ch = tid & 3;
    int gr = row0 + r;
    uint4 v = make_uint4(0, 0, 0, 0);
    if (gr < n) v = *reinterpret_cast<const uint4*>(A + (size_t)gr * K + kb + ch * 8);
    *reinterpret_cast<uint4*>(sA + r * LDSSTR + ch * 8) = v;
}

__device__ __forceinline__ void stage_B(const f16* __restrict__ Wt, f16* sB,
                                        int K, int kb, int tid) {
#pragma unroll
    for (int i = 0; i < 2; ++i) {
        int idx = tid + i * 256;
        int c = idx >> 2, ch = idx & 3;
        uint4 v = *reinterpret_cast<const uint4*>(Wt + (size_t)c * K + kb + ch * 8);
        *reinterpret_cast<uint4*>(sB + c * LDSSTR + ch * 8) = v;
    }
}

// Multi-output MFMA GEMM: A [n x K] fp16, blockIdx.y selects (W,bias,C).
template <int K, int NW, bool F32OUT>
__global__ __launch_bounds__(256) void k_mgemm(const f16* __restrict__ A,
                                               const f16* __restrict__ Wt0,
                                               const f16* __restrict__ Wt1,
                                               const f16* __restrict__ Wt2,
                                               const float* __restrict__ bias0,
                                               void* __restrict__ C0,
                                               void* __restrict__ C1,
                                               void* __restrict__ C2, int n) {
    __shared__ f16 sA[64 * LDSSTR];
    __shared__ f16 sB[128 * LDSSTR];

    const f16* Wt = Wt0;
    const float* bias = bias0;
    void* C = C0;
    if (NW > 1 && blockIdx.y == 1) { Wt = Wt1; bias = nullptr; C = C1; }
    if (NW > 2 && blockIdx.y == 2) { Wt = Wt2; bias = nullptr; C = C2; }

    const int tid = threadIdx.x;
    const int row0 = blockIdx.x * 64;
    const int wid = tid >> 6, l = tid & 63;
    const int wr = wid >> 1, wc = wid & 1;
    const int lr = l & 15, lk = (l >> 4) * 8;

    f32x4 acc[2][4];
#pragma unroll
    for (int m = 0; m < 2; ++m)
#pragma unroll
        for (int q = 0; q < 4; ++q) acc[m][q] = (f32x4){0.f, 0.f, 0.f, 0.f};

    for (int kt = 0; kt < K / 32; ++kt) {
        stage_A(A, sA, row0, K, kt * 32, tid, n);
        stage_B(Wt, sB, K, kt * 32, tid);
        __syncthreads();
        f16x8 aF[2], bF[4];
#pragma unroll
        for (int m = 0; m < 2; ++m)
            aF[m] = *reinterpret_cast<f16x8*>(sA + (wr * 32 + m * 16 + lr) * LDSSTR + lk);
#pragma unroll
        for (int q = 0; q < 4; ++q)
            bF[q] = *reinterpret_cast<f16x8*>(sB + (wc * 64 + q * 16 + lr) * LDSSTR + lk);
#pragma unroll
        for (int m = 0; m < 2; ++m)
#pragma unroll
            for (int q = 0; q < 4; ++q)
                acc[m][q] = __builtin_amdgcn_mfma_f32_16x16x32_f16(aF[m], bF[q],
                                                                   acc[m][q], 0, 0, 0);
        __syncthreads();
    }

    const int lr4 = (l >> 4) * 4;
#pragma unroll
    for (int m = 0; m < 2; ++m)
#pragma unroll
        for (int q = 0; q < 4; ++q) {
            int c = wc * 64 + q * 16 + (l & 15);
            float b = bias ? bias[c] : 0.0f;
#pragma unroll
            for (int reg = 0; reg < 4; ++reg) {
                int r = row0 + wr * 32 + m * 16 + lr4 + reg;
                if (r >= n) continue;
                float v = acc[m][q][reg] + b;
                if (F32OUT) ((float*)C)[(size_t)r * 128 + c] = v;
                else        ((f16*)C)[(size_t)r * 128 + c] = (f16)v;
            }
        }
}

// Gated-skip MFMA GEMM: G = sc@Wci + t0@Wco; z=sigmoid(G+bci+bco);
// out = z*t0 + (1-z)*sc, optional relu, fp16 out.
template <int RELU>
__global__ __launch_bounds__(256) void k_ggemm(const f16* __restrict__ Asc,
                                               const f16* __restrict__ At0,
                                               const f16* __restrict__ Wci,
                                               const f16* __restrict__ Wco,
                                               const float* __restrict__ bci,
                                               const float* __restrict__ bco,
                                               f16* __restrict__ C, int n) {
    __shared__ f16 sA[64 * LDSSTR];
    __shared__ f16 sB[128 * LDSSTR];

    const int tid = threadIdx.x;
    const int row0 = blockIdx.x * 64;
    const int wid = tid >> 6, l = tid & 63;
    const int wr = wid >> 1, wc = wid & 1;
    const int lr = l & 15, lk = (l >> 4) * 8;

    f32x4 acc[2][4];
#pragma unroll
    for (int m = 0; m < 2; ++m)
#pragma unroll
        for (int q = 0; q < 4; ++q) acc[m][q] = (f32x4){0.f, 0.f, 0.f, 0.f};

    for (int kt = 0; kt < 8; ++kt) {
        const f16* A = (kt < 4) ? Asc : At0;
        const f16* Wt = (kt < 4) ? Wci : Wco;
        int kb = (kt & 3) * 32;
        stage_A(A, sA, row0, 128, kb, tid, n);
        stage_B(Wt, sB, 128, kb, tid);
        __syncthreads();
        f16x8 aF[2], bF[4];
#pragma unroll
        for (int m = 0; m < 2; ++m)
            aF[m] = *reinterpret_cast<f16x8*>(sA + (wr * 32 + m * 16 + lr) * LDSSTR + lk);
#pragma unroll
        for (int q = 0; q < 4; ++q)
            bF[q] = *reinterpret_cast<f16x8*>(sB + (wc * 64 + q * 16 + lr) * LDSSTR + lk);
#pragma unroll
        for (int m = 0; m < 2; ++m)
#pragma unroll
            for (int q = 0; q < 4; ++q)
                acc[m][q] = __builtin_amdgcn_mfma_f32_16x16x32_f16(aF[m], bF[q],
                                                                   acc[m][q], 0, 0, 0);
        __syncthreads();
    }

    const int lr4 = (l >> 4) * 4;
#pragma unroll
    for (int m = 0; m < 2; ++m)
#pragma unroll
        for (int q = 0; q < 4; ++q) {
            int c = wc * 64 + q * 16 + (l & 15);
            float b = bci[c] + bco[c];
#pragma unroll
            for (int reg = 0; reg < 4; ++reg) {
                int r = row0 + wr * 32 + m * 16 + lr4 + reg;
                if (r >= n) continue;
                float v = acc[m][q][reg] + b;
                float z = 1.0f / (1.0f + __expf(-v));
                float o = (float)At0[(size_t)r * 128 + c];
                float s = (float)Asc[(size_t)r * 128 + c];
                float outv = z * o + (1.0f - z) * s;
                if (RELU) outv = fmaxf(outv, 0.0f);
                C[(size_t)r * 128 + c] = (f16)outv;
            }
        }
}

// ---------------------------------------------------------------------------
extern "C" void kernel_launch(void* const* d_in, const int* in_sizes, int n_in,
                              void* d_out, int out_size, void* d_ws, size_t ws_size,
                              hipStream_t stream) {
    const float* x    = (const float*)d_in[0];
    const int*   row  = (const int*)d_in[1];
    const int*   col  = (const int*)d_in[2];
    const float* W_sc = (const float*)d_in[3];
    const float* W_ci = (const float*)d_in[4];
    const float* b_ci = (const float*)d_in[5];
    const float* W_co = (const float*)d_in[6];
    const float* b_co = (const float*)d_in[7];
    const float* W0   = (const float*)d_in[8];
    const float* b0   = (const float*)d_in[9];
    const float* W1   = (const float*)d_in[10];
    const float* b1   = (const float*)d_in[11];
    const float* W2   = (const float*)d_in[12];
    const float* b2   = (const float*)d_in[13];
    const float* Wf   = (const float*)d_in[14];
    const float* bf   = (const float*)d_in[15];
    float* out = (float*)d_out;

    char* p = (char*)d_ws;
    auto alloc = [&](size_t bytes) {
        char* q = p;
        p += (bytes + 255) & ~(size_t)255;
        return q;
    };
    int*   cnt   = (int*)alloc((size_t)NN * CPAD * 4);  // padded: 1 counter / 64B
    int*   rp    = (int*)alloc((NN + 1) * 4);
    int*   bsum  = (int*)alloc(256 * 4);
    float* invd  = (float*)alloc(NN * 4);
    int*   ci    = (int*)alloc(EE * 4);
    int*   eslot = (int*)alloc(EE * 4);
    f16*   x_h   = (f16*)alloc((size_t)NN * 256 * 2);
    f16*   sc_h  = (f16*)alloc((size_t)NN * 128 * 2);
    f16*   T_h   = (f16*)alloc((size_t)NN * 128 * 2);
    f16*   P_h   = (f16*)alloc((size_t)NN * 128 * 2);
    f16*   t0_h  = (f16*)alloc((size_t)NN * 128 * 2);
    f16*   t1_h  = (f16*)alloc((size_t)NN * 128 * 2);
    // transposed fp16 weights [128 x K]
    f16* W0t_t = (f16*)alloc(256 * 128 * 2);
    f16* W0b_t = (f16*)alloc(256 * 128 * 2);
    f16* Wsc_t = (f16*)alloc(256 * 128 * 2);
    f16* W1t_t = (f16*)alloc(128 * 128 * 2);
    f16* W1b_t = (f16*)alloc(128 * 128 * 2);
    f16* W2t_t = (f16*)alloc(128 * 128 * 2);
    f16* W2b_t = (f16*)alloc(128 * 128 * 2);
    f16* Wci_t = (f16*)alloc(128 * 128 * 2);
    f16* Wco_t = (f16*)alloc(128 * 128 * 2);
    f16* Wf_t  = (f16*)alloc(128 * 128 * 2);

    const int NB_N  = (NN + 255) / 256;   // 196
    const int NB_E  = (EE + 255) / 256;   // 6250
    const int GB    = (NN + 63) / 64;     // 782 mfma-gemm row-blocks
    const int AGG_B = (NN + 15) / 16;     // 3125 blocks (16 nodes/block)

    // ---- prep: convert x, zero counters, convert+transpose weights ----
    const int N4   = NN * 256 / 4;               // 3,200,000 float4
    const int NZ4  = NN * CPAD / 4;              // 200,000 int4
    const int ZB0  = (N4 + 255) / 256;           // 12500
    const int WB0  = ZB0 + (NZ4 + 255) / 256;    // +782
    const int WBLK = 84;
    const int WTOT = 3 * 32768 + 7 * 16384;      // 212,992
    WPtrs wp;
    wp.s[0] = W0;             wp.d[0] = W0t_t;
    wp.s[1] = W0 + 256 * 128; wp.d[1] = W0b_t;
    wp.s[2] = W_sc;           wp.d[2] = Wsc_t;
    wp.s[3] = W1;             wp.d[3] = W1t_t;
    wp.s[4] = W1 + 128 * 128; wp.d[4] = W1b_t;
    wp.s[5] = W2;             wp.d[5] = W2t_t;
    wp.s[6] = W2 + 128 * 128; wp.d[6] = W2b_t;
    wp.s[7] = W_ci;           wp.d[7] = Wci_t;
    wp.s[8] = W_co;           wp.d[8] = Wco_t;
    wp.s[9] = Wf;             wp.d[9] = Wf_t;
    k_prep<<<WB0 + WBLK, 256, 0, stream>>>(x, x_h, N4, cnt, NZ4, wp, WTOT,
                                           ZB0, WB0, WBLK);

    // ---- graph structure ----
    k_slot<<<NB_E, 256, 0, stream>>>(row, cnt, eslot, EE);
    k_scan1<<<NB_N, 256, 0, stream>>>(cnt, bsum, NN);
    k_scan3<<<NB_N, 256, 0, stream>>>(cnt, bsum, rp, invd, NN, NB_N);
    k_fill8<<<dim3(NB_E, NPASS), 256, 0, stream>>>(row, col, eslot, rp, ci, EE);

    // ---- layer 0:  T = x@W0top + b0, P = x@W0bot, sc = x@W_sc ----
    k_mgemm<256, 3, false><<<dim3(GB, 3), 256, 0, stream>>>(
        x_h, W0t_t, W0b_t, Wsc_t, b0, T_h, P_h, sc_h, NN);
    k_agg2h<<<AGG_B, 256, 0, stream>>>(P_h, rp, ci, invd, T_h, t0_h, NN);    // o1
    k_ggemm<1><<<GB, 256, 0, stream>>>(sc_h, t0_h, Wci_t, Wco_t,
                                       b_ci, b_co, t1_h, NN);                // o3

    // ---- layer 1 ----
    k_mgemm<128, 2, false><<<dim3(GB, 2), 256, 0, stream>>>(
        t1_h, W1t_t, W1b_t, nullptr, b1, T_h, P_h, nullptr, NN);
    k_agg2h<<<AGG_B, 256, 0, stream>>>(P_h, rp, ci, invd, T_h, t0_h, NN);    // o4
    k_ggemm<1><<<GB, 256, 0, stream>>>(sc_h, t0_h, Wci_t, Wco_t,
                                       b_ci, b_co, t1_h, NN);                // o6

    // ---- layer 2 ----
    k_mgemm<128, 2, false><<<dim3(GB, 2), 256, 0, stream>>>(
        t1_h, W2t_t, W2b_t, nullptr, b2, T_h, P_h, nullptr, NN);
    k_agg2h<<<AGG_B, 256, 0, stream>>>(P_h, rp, ci, invd, T_h, t0_h, NN);    // o7
    k_ggemm<0><<<GB, 256, 0, stream>>>(sc_h, t0_h, Wci_t, Wco_t,
                                       b_ci, b_co, t1_h, NN);                // o8

    // ---- classifier: out = t1 @ Wf + bf (fp32 out) ----
    k_mgemm<128, 1, true><<<GB, 256, 0, stream>>>(
        t1_h, Wf_t, nullptr, nullptr, bf, out, nullptr, nullptr, NN);
}